// Round 1
// baseline (625.493 us; speedup 1.0000x reference)
//
#include <hip/hip_runtime.h>
#include <hip/hip_bf16.h>

typedef __bf16 bf16_t;
typedef __attribute__((ext_vector_type(4))) __bf16 bf16x4;
typedef __attribute__((ext_vector_type(8))) __bf16 bf16x8;
typedef __attribute__((ext_vector_type(4))) float f32x4;

#define NEGV (-1e30f)

// Problem constants
#define BB 4
#define TT 200
#define UU 50
#define U1 51
#define VV 1024
#define DD 512
#define HH 640
#define RTOT (BB*TT*U1)      // 40800
#define RPAD 40832           // 638*64
#define SS 101               // 2U+1

// ---------------- generic small fp32 GEMM: C = A(MxK) @ B(KxN) [+bias] ----
__global__ void gemm_f32(const float* __restrict__ A, int lda,
                         const float* __restrict__ Bm, int ldb,
                         float* __restrict__ C, int ldc,
                         int M, int N, int K,
                         const float* __restrict__ bias)
{
    __shared__ float As[32][33];
    __shared__ float Bs[32][33];
    const int tid = threadIdx.x;
    const int bm = blockIdx.x * 32, bn = blockIdx.y * 32;
    const int ty = tid >> 4, tx = tid & 15;
    float c00 = 0.f, c01 = 0.f, c10 = 0.f, c11 = 0.f;
    for (int k0 = 0; k0 < K; k0 += 32) {
        for (int e = tid; e < 1024; e += 256) {
            int r = e >> 5, c = e & 31;
            int gr = bm + r;
            As[r][c] = (gr < M) ? A[gr * lda + k0 + c] : 0.f;
            Bs[r][c] = Bm[(k0 + r) * ldb + bn + c];
        }
        __syncthreads();
#pragma unroll
        for (int k = 0; k < 32; ++k) {
            float a0 = As[ty * 2][k], a1 = As[ty * 2 + 1][k];
            float b0 = Bs[k][tx * 2], b1 = Bs[k][tx * 2 + 1];
            c00 += a0 * b0; c01 += a0 * b1; c10 += a1 * b0; c11 += a1 * b1;
        }
        __syncthreads();
    }
    int row0 = bm + ty * 2, col0 = bn + tx * 2;
    float bb0 = bias ? bias[col0] : 0.f;
    float bb1 = bias ? bias[col0 + 1] : 0.f;
    if (row0 < M)     { C[row0 * ldc + col0] = c00 + bb0; C[row0 * ldc + col0 + 1] = c01 + bb1; }
    if (row0 + 1 < M) { C[(row0 + 1) * ldc + col0] = c10 + bb0; C[(row0 + 1) * ldc + col0 + 1] = c11 + bb1; }
}

// ---------------- pack W_out (640x1024 f32) into bf16 MFMA B-fragment order
// element index: ((nt*20+kk)*64 + l)*8 + j  -> B[k][v], v = nt*16+(l&15),
// k = kk*32 + (l>>4)*4 + (j&3) + 16*(j>>2)   (same formula used for A reads;
// any k-permutation mismatch vs HW cancels since A and B share it)
__global__ void pack_wfrag(const float* __restrict__ W, bf16_t* __restrict__ Wf)
{
    int e = blockIdx.x * 256 + threadIdx.x;   // 655360 total
    if (e >= 64 * 20 * 64 * 8) return;
    int j  = e & 7;
    int l  = (e >> 3) & 63;
    int kk = (e >> 9) % 20;
    int nt = e / 10240;
    int v = nt * 16 + (l & 15);
    int k = kk * 32 + ((l >> 4) << 2) + (j & 3) + ((j >> 2) << 4);
    Wf[e] = (bf16_t)W[k * VV + v];
}

// ---------------- fused joint build + bf16 MFMA GEMM + row-LSE + gather ----
__global__ __launch_bounds__(512)
void joint_gemm(const float* __restrict__ enc,   // (800,640)
                const float* __restrict__ pred,  // (204,640)
                const float* __restrict__ bj,    // (640)
                const bf16_t* __restrict__ Wf,   // packed fragments
                const float* __restrict__ bo,    // (1024)
                const int* __restrict__ target,  // (4,50)
                float* __restrict__ blank_buf,   // (40832)
                float* __restrict__ emit_buf)    // (40832)
{
    __shared__ bf16_t Asm[64 * 648];             // 64 rows x 640 (+8 pad)
    __shared__ int rowBT[64], rowBU[64], rowTG[64];
    __shared__ float cm[64][2], cs[64][2], ce[64][2], cb[64][2];
    const int tid = threadIdx.x;
    const int blk = blockIdx.x;

    if (tid < 64) {
        int r = blk * 64 + tid; if (r > RTOT - 1) r = RTOT - 1;
        int b = r / (TT * U1); int rem = r - b * (TT * U1);
        int t = rem / U1;      int u = rem - t * U1;
        rowBT[tid] = b * TT + t;
        rowBU[tid] = b * U1 + u;
        rowTG[tid] = (u < UU) ? target[b * UU + u] : -1;
    }
    __syncthreads();

    // build A tile: tanh(enc + pred + b_joint), fp32 -> bf16
    for (int e = tid; e < 64 * HH; e += 512) {
        int i = e / HH, c = e - i * HH;
        float v = enc[rowBT[i] * HH + c] + pred[rowBU[i] * HH + c] + bj[c];
        float ex = __expf(2.f * v);
        Asm[i * 648 + c] = (bf16_t)(1.f - 2.f / (ex + 1.f));
    }
    __syncthreads();

    const int l = tid & 63, w = tid >> 6;
    const int lrow = l & 15, lhi = l >> 4;
    const int band = w & 3, half = w >> 2;    // 4 row-bands x 2 N-halves
    const int arow = band * 16 + lrow;

    float m[4], s[4], eL[4], bL[4];
    int tg[4];
#pragma unroll
    for (int i = 0; i < 4; ++i) {
        m[i] = NEGV; s[i] = 0.f; eL[i] = NEGV; bL[i] = NEGV;
        tg[i] = rowTG[band * 16 + lhi * 4 + i];
    }
    const bf16_t* ab = &Asm[arow * 648 + lhi * 4];

    for (int n4 = half * 8; n4 < half * 8 + 8; ++n4) {
        f32x4 acc0 = {0,0,0,0}, acc1 = {0,0,0,0}, acc2 = {0,0,0,0}, acc3 = {0,0,0,0};
        const bf16_t* wp = Wf + (size_t)(n4 * 4) * 10240 + l * 8;
#pragma unroll
        for (int kk = 0; kk < 20; ++kk) {
            bf16x4 a0 = *(const bf16x4*)(ab + kk * 32);
            bf16x4 a1 = *(const bf16x4*)(ab + kk * 32 + 16);
            bf16x8 af;
            af[0] = a0[0]; af[1] = a0[1]; af[2] = a0[2]; af[3] = a0[3];
            af[4] = a1[0]; af[5] = a1[1]; af[6] = a1[2]; af[7] = a1[3];
            bf16x8 b0 = *(const bf16x8*)(wp + (0 * 20 + kk) * 512);
            bf16x8 b1 = *(const bf16x8*)(wp + (1 * 20 + kk) * 512);
            bf16x8 b2 = *(const bf16x8*)(wp + (2 * 20 + kk) * 512);
            bf16x8 b3 = *(const bf16x8*)(wp + (3 * 20 + kk) * 512);
            acc0 = __builtin_amdgcn_mfma_f32_16x16x32_bf16(af, b0, acc0, 0, 0, 0);
            acc1 = __builtin_amdgcn_mfma_f32_16x16x32_bf16(af, b1, acc1, 0, 0, 0);
            acc2 = __builtin_amdgcn_mfma_f32_16x16x32_bf16(af, b2, acc2, 0, 0, 0);
            acc3 = __builtin_amdgcn_mfma_f32_16x16x32_bf16(af, b3, acc3, 0, 0, 0);
        }
        // epilogue: D layout col=lane&15, row=(lane>>4)*4+i  [measured m89]
        auto epi = [&](const f32x4& a, int nt) {
            int col = (n4 * 4 + nt) * 16 + lrow;
            float bov = bo[col];
#pragma unroll
            for (int i = 0; i < 4; ++i) {
                float x = a[i] + bov;
                eL[i] = (col == tg[i]) ? x : eL[i];
                bL[i] = (col == VV - 1) ? x : bL[i];
                float mn = fmaxf(m[i], x);
                s[i] = s[i] * __expf(m[i] - mn) + __expf(x - mn);
                m[i] = mn;
            }
        };
        epi(acc0, 0); epi(acc1, 1); epi(acc2, 2); epi(acc3, 3);
    }

    // reduce across the 16 lanes sharing the same rows (xor 1,2,4,8)
#pragma unroll
    for (int d = 1; d < 16; d <<= 1) {
#pragma unroll
        for (int i = 0; i < 4; ++i) {
            float mo  = __shfl_xor(m[i], d);
            float so  = __shfl_xor(s[i], d);
            float eo  = __shfl_xor(eL[i], d);
            float bo2 = __shfl_xor(bL[i], d);
            float mn = fmaxf(m[i], mo);
            s[i] = s[i] * __expf(m[i] - mn) + so * __expf(mo - mn);
            m[i] = mn;
            eL[i] = fmaxf(eL[i], eo);
            bL[i] = fmaxf(bL[i], bo2);
        }
    }
    if (lrow == 0) {
#pragma unroll
        for (int i = 0; i < 4; ++i) {
            int rr = band * 16 + lhi * 4 + i;
            cm[rr][half] = m[i];  cs[rr][half] = s[i];
            ce[rr][half] = eL[i]; cb[rr][half] = bL[i];
        }
    }
    __syncthreads();
    if (tid < 64) {
        float m0 = cm[tid][0], m1 = cm[tid][1];
        float M = fmaxf(m0, m1);
        float ss = cs[tid][0] * __expf(m0 - M) + cs[tid][1] * __expf(m1 - M);
        float lse = M + __logf(ss);
        int gid = blk * 64 + tid;
        if (gid < RTOT) {
            blank_buf[gid] = fmaxf(cb[tid][0], cb[tid][1]) - lse;
            emit_buf[gid]  = fmaxf(ce[tid][0], ce[tid][1]) - lse;
        }
    }
}

// ---------------- CTC: per-(b,t) row LSE + gather ext symbols --------------
__global__ void ctc_prep(const float* __restrict__ logits, const int* __restrict__ target,
                         float* __restrict__ lp_ext)
{
    int bt = blockIdx.x;            // 0..799
    int b = bt / TT;
    const float* row = logits + (size_t)bt * VV;
    int tid = threadIdx.x;          // 256
    int w = tid >> 6;
    __shared__ float red[4], red2[4];

    float mx = NEGV;
    for (int i = tid; i < VV; i += 256) mx = fmaxf(mx, row[i]);
#pragma unroll
    for (int d = 1; d < 64; d <<= 1) mx = fmaxf(mx, __shfl_xor(mx, d));
    if ((tid & 63) == 0) red[w] = mx;
    __syncthreads();
    mx = fmaxf(fmaxf(red[0], red[1]), fmaxf(red[2], red[3]));

    float sm = 0.f;
    for (int i = tid; i < VV; i += 256) sm += __expf(row[i] - mx);
#pragma unroll
    for (int d = 1; d < 64; d <<= 1) sm += __shfl_xor(sm, d);
    if ((tid & 63) == 0) red2[w] = sm;
    __syncthreads();
    sm = red2[0] + red2[1] + red2[2] + red2[3];
    float lse = mx + __logf(sm);

    if (tid < SS) {
        int tok = (tid & 1) ? target[b * UU + (tid >> 1)] : (VV - 1);
        lp_ext[bt * SS + tid] = row[tok] - lse;
    }
}

// ---------------- RNNT DP: one wave per batch, shfl prefix scans -----------
__device__ __forceinline__ float lae(float x, float y)
{
    float mx = fmaxf(x, y);
    return mx + __logf(__expf(x - mx) + __expf(y - mx));
}

__global__ void rnnt_dp(const float* __restrict__ blank_buf, const float* __restrict__ emit_buf,
                        const int* __restrict__ frame_len, const int* __restrict__ tgt_len,
                        float* __restrict__ loss)
{
    int b = blockIdx.x;
    int u = threadIdx.x;            // 64 lanes, u<51 active
    int fl = frame_len[b], tl = tgt_len[b];
    bool act = (u < U1);

    // t = 0: alpha0 = exclusive cumsum of emit[b,0,:]
    float x = (u < UU) ? emit_buf[(b * TT + 0) * U1 + u] : 0.f;
    float sscan = x;
#pragma unroll
    for (int d = 1; d < 64; d <<= 1) { float o = __shfl_up(sscan, d); if (u >= d) sscan += o; }
    float alpha = sscan - x;
    if (fl - 1 == 0 && u == tl) loss[b] = -(alpha + blank_buf[(b * TT + 0) * U1 + u]);

    for (int t = 1; t < TT; ++t) {
        float a = alpha + blank_buf[(b * TT + (t - 1)) * U1 + u];
        float e = (u < UU) ? emit_buf[(b * TT + t) * U1 + u] : 0.f;
        float es = e;
#pragma unroll
        for (int d = 1; d < 64; d <<= 1) { float o = __shfl_up(es, d); if (u >= d) es += o; }
        float E = es - e;                 // exclusive cumsum
        float z = act ? (a - E) : NEGV;
#pragma unroll
        for (int d = 1; d < 64; d <<= 1) { float o = __shfl_up(z, d); if (u >= d) z = lae(z, o); }
        alpha = E + z;
        if (t == fl - 1 && u == tl) loss[b] = -(alpha + blank_buf[(b * TT + t) * U1 + u]);
    }
}

// ---------------- CTC DP: 101 states in LDS, relax over t ------------------
__global__ void ctc_dp(const float* __restrict__ lp_ext, const int* __restrict__ target,
                       const int* __restrict__ frame_len, const int* __restrict__ tgt_len,
                       float* __restrict__ loss)
{
    int b = blockIdx.x;
    int s = threadIdx.x;            // 128, s<101 active
    int fl = frame_len[b], tl = tgt_len[b];
    __shared__ float A[104];
    bool act = (s < SS);
    bool skip = false;
    if (act && (s & 1) && s >= 3)
        skip = target[b * UU + (s >> 1)] != target[b * UU + (s >> 1) - 1];

    float a0 = NEGV;
    if (s == 0) a0 = lp_ext[(b * TT) * SS + 0];
    else if (s == 1) a0 = lp_ext[(b * TT) * SS + 1];
    if (act) A[s] = a0;
    __syncthreads();
    if (fl - 1 == 0 && s == 0) loss[b] = -lae(A[2 * tl], A[2 * tl - 1]);

    for (int t = 1; t < TT; ++t) {
        float p0 = act ? A[s] : NEGV;
        float p1 = (act && s >= 1) ? A[s - 1] : NEGV;
        float p2 = (act && skip) ? A[s - 2] : NEGV;
        __syncthreads();
        if (act) {
            float lp = lp_ext[(b * TT + t) * SS + s];
            float mx = fmaxf(fmaxf(p0, p1), p2);
            A[s] = lp + mx + __logf(__expf(p0 - mx) + __expf(p1 - mx) + __expf(p2 - mx));
        }
        __syncthreads();
        if (t == fl - 1 && s == 0) loss[b] = -lae(A[2 * tl], A[2 * tl - 1]);
    }
}

// ---------------- final combine -------------------------------------------
__global__ void combine(const float* __restrict__ lr, const float* __restrict__ lc,
                        float* __restrict__ out)
{
    float r = 0.25f * (lr[0] + lr[1] + lr[2] + lr[3]);
    float c = 0.25f * (lc[0] + lc[1] + lc[2] + lc[3]);
    out[0] = r + 0.3f * c;
}

extern "C" void kernel_launch(void* const* d_in, const int* in_sizes, int n_in,
                              void* d_out, int out_size, void* d_ws, size_t ws_size,
                              hipStream_t stream)
{
    const float* x_enc   = (const float*)d_in[0];
    const float* x_dec   = (const float*)d_in[1];
    const int*   target  = (const int*)d_in[2];
    const int*   frame_l = (const int*)d_in[3];
    const int*   tgt_l   = (const int*)d_in[4];
    const float* W_ctc   = (const float*)d_in[5];
    const float* b_ctc   = (const float*)d_in[6];
    const float* W_enc   = (const float*)d_in[7];
    const float* W_pred  = (const float*)d_in[8];
    const float* b_joint = (const float*)d_in[9];
    const float* W_out   = (const float*)d_in[10];
    const float* b_out   = (const float*)d_in[11];
    float* out = (float*)d_out;

    float* wsf        = (float*)d_ws;
    float* enc_proj   = wsf;                      // 800*640  = 512000
    float* pred_proj  = enc_proj + 512000;        // 204*640  = 130560
    float* ctc_logits = pred_proj + 130560;       // 800*1024 = 819200
    float* blank_buf  = ctc_logits + 819200;      // 40832
    float* emit_buf   = blank_buf + 40832;        // 40832
    float* lp_ext     = emit_buf + 40832;         // 800*101  = 80800
    float* loss_rnnt  = lp_ext + 80800;           // 4
    float* loss_ctc   = loss_rnnt + 4;            // 4
    bf16_t* Wfrag     = (bf16_t*)(loss_ctc + 4);  // 655360 bf16 (byte off 6496928, 16B aligned)

    // small fp32 GEMMs
    gemm_f32<<<dim3(25, 20), 256, 0, stream>>>(x_enc, DD, W_enc, HH, enc_proj, HH, 800, HH, DD, nullptr);
    gemm_f32<<<dim3(7, 20), 256, 0, stream>>>(x_dec, HH, W_pred, HH, pred_proj, HH, 204, HH, HH, nullptr);
    gemm_f32<<<dim3(25, 32), 256, 0, stream>>>(x_enc, DD, W_ctc, VV, ctc_logits, VV, 800, VV, DD, b_ctc);
    // pack W_out fragments
    pack_wfrag<<<2560, 256, 0, stream>>>(W_out, Wfrag);
    // dominant fused kernel
    joint_gemm<<<RPAD / 64, 512, 0, stream>>>(enc_proj, pred_proj, b_joint, Wfrag, b_out,
                                              target, blank_buf, emit_buf);
    // CTC log-prob prep
    ctc_prep<<<800, 256, 0, stream>>>(ctc_logits, target, lp_ext);
    // DPs
    rnnt_dp<<<4, 64, 0, stream>>>(blank_buf, emit_buf, frame_l, tgt_l, loss_rnnt);
    ctc_dp<<<4, 128, 0, stream>>>(lp_ext, target, frame_l, tgt_l, loss_ctc);
    // combine
    combine<<<1, 1, 0, stream>>>(loss_rnnt, loss_ctc, out);
}

// Round 2
// 347.798 us; speedup vs baseline: 1.7984x; 1.7984x over previous
//
#include <hip/hip_runtime.h>
#include <hip/hip_bf16.h>

typedef __bf16 bf16_t;
typedef __attribute__((ext_vector_type(4))) __bf16 bf16x4;
typedef __attribute__((ext_vector_type(8))) __bf16 bf16x8;
typedef __attribute__((ext_vector_type(4))) float f32x4;

#define NEGV (-1e30f)

// Problem constants
#define BB 4
#define TT 200
#define UU 50
#define U1 51
#define VV 1024
#define DD 512
#define HH 640
#define RTOT (BB*TT*U1)      // 40800
#define RPAD 40832           // 638*64
#define SS 101

__device__ __forceinline__ float lae(float a, float b) {
    float mx = fmaxf(a, b);
    return mx + __logf(__expf(a - mx) + __expf(b - mx));
}
__device__ __forceinline__ float lae3(float a, float b, float c) {
    float mx = fmaxf(fmaxf(a, b), c);
    return mx + __logf(__expf(a - mx) + __expf(b - mx) + __expf(c - mx));
}
__device__ __forceinline__ float tanh_fast(float x) {
    float ex = __expf(2.f * x);
    return 1.f - 2.f / (ex + 1.f);
}

// ---------------- pack fp32 (K x N) weight into bf16 MFMA B-fragment order.
// e = ((nt*K32 + kk)*64 + l)*8 + j ; v = nt*16+(l&15) ;
// k = kk*32 + ((l>>4)<<2) + (j&3) + ((j>>2)<<4)   (same k-map as A build)
__device__ __forceinline__ void pack_seg(const float* __restrict__ W, bf16_t* __restrict__ Wf,
                                         int e, int K32, int N)
{
    int j  = e & 7;
    int l  = (e >> 3) & 63;
    int kk = (e >> 9) % K32;
    int nt = e / (K32 * 512);
    int v = nt * 16 + (l & 15);
    int k = kk * 32 + ((l >> 4) << 2) + (j & 3) + ((j >> 2) << 4);
    Wf[e] = (bf16_t)W[(size_t)k * N + v];
}

__global__ void pack_all(const float* __restrict__ Wout, const float* __restrict__ Wenc,
                         const float* __restrict__ Wpred, const float* __restrict__ Wctc,
                         bf16_t* __restrict__ FOut, bf16_t* __restrict__ FEnc,
                         bf16_t* __restrict__ FPred, bf16_t* __restrict__ FCtc)
{
    int e = blockIdx.x * 256 + threadIdx.x;
    if (e < 655360) { pack_seg(Wout, FOut, e, 20, 1024); return; }
    e -= 655360;
    if (e < 327680) { pack_seg(Wenc, FEnc, e, 16, 640); return; }
    e -= 327680;
    if (e < 409600) { pack_seg(Wpred, FPred, e, 20, 640); return; }
    e -= 409600;
    pack_seg(Wctc, FCtc, e, 16, 1024);
}

// ---------------- generic MFMA GEMM: C = A(MxK fp32) @ Wf(packed bf16) -----
template<int K32, int L, bool LSE>
__device__ void gemm_dev(const float* __restrict__ A, int M, int rowbase, int K,
                         const bf16_t* __restrict__ Wf, const float* __restrict__ bias,
                         float* __restrict__ C, float* __restrict__ lse_out, int N,
                         bf16_t* Atile, float (*ps)[8])
{
    const int tid = threadIdx.x;
    // build A tile (64 x K) in fragment order, bf16
#pragma unroll 2
    for (int it = 0; it < K32; ++it) {
        int e4 = tid + it * 512;
        int row = e4 / (K32 * 8);
        int c4 = e4 - row * (K32 * 8);
        int c = c4 * 4;
        int arow = rowbase + row; if (arow > M - 1) arow = M - 1;
        const float4 va = *(const float4*)&A[(size_t)arow * K + c];
        int kk = c >> 5, c32 = c & 31, lhi = (c32 >> 2) & 3, b4 = c32 >> 4;
        int j = row >> 4, lrow = row & 15;
        bf16x4 v;
        v[0] = (bf16_t)va.x; v[1] = (bf16_t)va.y; v[2] = (bf16_t)va.z; v[3] = (bf16_t)va.w;
        *(bf16x4*)&Atile[(size_t)(((j * K32 + kk) * 64 + lhi * 16 + lrow) * 8 + b4 * 4)] = v;
    }
    __syncthreads();

    const int l = tid & 63, w = tid >> 6;
    const int lrow = l & 15, lhi = l >> 4;

    f32x4 acc[4][L];
#pragma unroll
    for (int j = 0; j < 4; ++j)
#pragma unroll
        for (int li = 0; li < L; ++li) acc[j][li] = f32x4{0.f, 0.f, 0.f, 0.f};

    for (int kk = 0; kk < K32; ++kk) {
        bf16x8 a[4];
#pragma unroll
        for (int j = 0; j < 4; ++j)
            a[j] = *(const bf16x8*)&Atile[(size_t)(((j * K32 + kk) * 64 + l) * 8)];
#pragma unroll
        for (int li = 0; li < L; ++li) {
            bf16x8 b = *(const bf16x8*)&Wf[(size_t)(((w * L + li) * K32 + kk) * 64 + l) * 8];
#pragma unroll
            for (int j = 0; j < 4; ++j)
                acc[j][li] = __builtin_amdgcn_mfma_f32_16x16x32_bf16(a[j], b, acc[j][li], 0, 0, 0);
        }
    }

    float se[4][4];
    if (LSE) {
#pragma unroll
        for (int j = 0; j < 4; ++j)
#pragma unroll
            for (int i = 0; i < 4; ++i) se[j][i] = 0.f;
    }
#pragma unroll
    for (int j = 0; j < 4; ++j)
#pragma unroll
        for (int li = 0; li < L; ++li) {
            int col = (w * L + li) * 16 + lrow;
            float bv = bias ? bias[col] : 0.f;
#pragma unroll
            for (int i = 0; i < 4; ++i) {
                int grow = rowbase + 16 * j + lhi * 4 + i;
                float x = acc[j][li][i] + bv;
                if (grow < M) C[(size_t)grow * N + col] = x;
                if (LSE) se[j][i] += __expf(x);
            }
        }
    if (LSE) {
#pragma unroll
        for (int d = 1; d < 16; d <<= 1)
#pragma unroll
            for (int j = 0; j < 4; ++j)
#pragma unroll
                for (int i = 0; i < 4; ++i) se[j][i] += __shfl_xor(se[j][i], d);
        if (lrow == 0) {
#pragma unroll
            for (int j = 0; j < 4; ++j)
#pragma unroll
                for (int i = 0; i < 4; ++i) ps[16 * j + lhi * 4 + i][w] = se[j][i];
        }
        __syncthreads();
        if (tid < 64) {
            float s = 0.f;
#pragma unroll
            for (int w0 = 0; w0 < 8; ++w0) s += ps[tid][w0];
            int grow = rowbase + tid;
            if (grow < M) lse_out[grow] = __logf(s);
        }
    }
}

__global__ __launch_bounds__(512)
void mfma_gemm3(const float* __restrict__ x_enc, const float* __restrict__ x_dec,
                const bf16_t* __restrict__ FEnc, const bf16_t* __restrict__ FPred,
                const bf16_t* __restrict__ FCtc, const float* __restrict__ b_ctc,
                float* __restrict__ enc_proj, float* __restrict__ pred_proj,
                float* __restrict__ ctc_logits, float* __restrict__ ctc_lse)
{
    __shared__ bf16_t Atile[40960];
    __shared__ float ps[64][8];
    int blk = blockIdx.x;
    if (blk < 13)
        gemm_dev<16, 5, false>(x_enc, 800, blk * 64, 512, FEnc, nullptr, enc_proj, nullptr, 640, Atile, ps);
    else if (blk < 17)
        gemm_dev<20, 5, false>(x_dec, 204, (blk - 13) * 64, 640, FPred, nullptr, pred_proj, nullptr, 640, Atile, ps);
    else
        gemm_dev<16, 8, true>(x_enc, 800, (blk - 17) * 64, 512, FCtc, b_ctc, ctc_logits, ctc_lse, 1024, Atile, ps);
}

// ---------------- fused joint build + MFMA GEMM + row-LSE + gather ---------
__global__ __launch_bounds__(512)
void joint_gemm(const float* __restrict__ enc,   // (800,640)
                const float* __restrict__ pred,  // (204,640)
                const float* __restrict__ bj,    // (640)
                const bf16_t* __restrict__ Wf,   // packed (K32=20, NT=64)
                const float* __restrict__ bo,    // (1024)
                const int* __restrict__ target,  // (4,50)
                float* __restrict__ blank_buf, float* __restrict__ emit_buf)
{
    __shared__ bf16_t Afrag[40960];              // 64 rows x 640 K, frag order
    __shared__ int rowBT[64], rowBU[64], rowTG[64];
    __shared__ float ps[64][8], pe[64][8], pb[64][8];
    const int tid = threadIdx.x;
    const int blk = blockIdx.x;

    if (tid < 64) {
        int r = blk * 64 + tid; if (r > RTOT - 1) r = RTOT - 1;
        int b = r / (TT * U1); int rem = r - b * (TT * U1);
        int t = rem / U1;      int u = rem - t * U1;
        rowBT[tid] = b * TT + t;
        rowBU[tid] = b * U1 + u;
        rowTG[tid] = (u < UU) ? target[b * UU + u] : -1;
    }
    __syncthreads();

    // build tanh(enc+pred+bj) tile directly in fragment order
#pragma unroll 2
    for (int it = 0; it < 20; ++it) {
        int e4 = tid + it * 512;
        int row = e4 / 160, c4 = e4 - row * 160;
        int c = c4 * 4;
        const float4 ve = *(const float4*)&enc[(size_t)rowBT[row] * HH + c];
        const float4 vp = *(const float4*)&pred[(size_t)rowBU[row] * HH + c];
        const float4 vb = *(const float4*)&bj[c];
        int kk = c >> 5, c32 = c & 31, lhi = (c32 >> 2) & 3, b4 = c32 >> 4;
        int j = row >> 4, lrow = row & 15;
        bf16x4 v;
        v[0] = (bf16_t)tanh_fast(ve.x + vp.x + vb.x);
        v[1] = (bf16_t)tanh_fast(ve.y + vp.y + vb.y);
        v[2] = (bf16_t)tanh_fast(ve.z + vp.z + vb.z);
        v[3] = (bf16_t)tanh_fast(ve.w + vp.w + vb.w);
        *(bf16x4*)&Afrag[(size_t)(((j * 20 + kk) * 64 + lhi * 16 + lrow) * 8 + b4 * 4)] = v;
    }
    __syncthreads();

    const int l = tid & 63, w = tid >> 6;
    const int lrow = l & 15, lhi = l >> 4;

    f32x4 acc[4][8];
#pragma unroll
    for (int j = 0; j < 4; ++j)
#pragma unroll
        for (int li = 0; li < 8; ++li) acc[j][li] = f32x4{0.f, 0.f, 0.f, 0.f};

    for (int kk = 0; kk < 20; ++kk) {
        bf16x8 a[4];
#pragma unroll
        for (int j = 0; j < 4; ++j)
            a[j] = *(const bf16x8*)&Afrag[(size_t)(((j * 20 + kk) * 64 + l) * 8)];
#pragma unroll
        for (int li = 0; li < 8; ++li) {
            bf16x8 b = *(const bf16x8*)&Wf[(size_t)(((w * 8 + li) * 20 + kk) * 64 + l) * 8];
#pragma unroll
            for (int j = 0; j < 4; ++j)
                acc[j][li] = __builtin_amdgcn_mfma_f32_16x16x32_bf16(a[j], b, acc[j][li], 0, 0, 0);
        }
    }

    // epilogue: exp-sum (no max needed: |logit| <= sum|W_out col| ~ 10), gather
    int tg[4][4];
#pragma unroll
    for (int j = 0; j < 4; ++j)
#pragma unroll
        for (int i = 0; i < 4; ++i) tg[j][i] = rowTG[16 * j + lhi * 4 + i];

    float se[4][4], ee[4][4], bbv[4][4];
#pragma unroll
    for (int j = 0; j < 4; ++j)
#pragma unroll
        for (int i = 0; i < 4; ++i) { se[j][i] = 0.f; ee[j][i] = NEGV; bbv[j][i] = NEGV; }

#pragma unroll
    for (int li = 0; li < 8; ++li) {
        int col = (w * 8 + li) * 16 + lrow;
        float bv = bo[col];
#pragma unroll
        for (int j = 0; j < 4; ++j)
#pragma unroll
            for (int i = 0; i < 4; ++i) {
                float x = acc[j][li][i] + bv;
                se[j][i] += __expf(x);
                if (col == tg[j][i]) ee[j][i] = x;
                if (col == VV - 1) bbv[j][i] = x;
            }
    }
#pragma unroll
    for (int d = 1; d < 16; d <<= 1)
#pragma unroll
        for (int j = 0; j < 4; ++j)
#pragma unroll
            for (int i = 0; i < 4; ++i) {
                se[j][i] += __shfl_xor(se[j][i], d);
                ee[j][i] = fmaxf(ee[j][i], __shfl_xor(ee[j][i], d));
                bbv[j][i] = fmaxf(bbv[j][i], __shfl_xor(bbv[j][i], d));
            }
    if (lrow == 0) {
#pragma unroll
        for (int j = 0; j < 4; ++j)
#pragma unroll
            for (int i = 0; i < 4; ++i) {
                int r = 16 * j + lhi * 4 + i;
                ps[r][w] = se[j][i]; pe[r][w] = ee[j][i]; pb[r][w] = bbv[j][i];
            }
    }
    __syncthreads();
    if (tid < 64) {
        float s = 0.f, e = NEGV, bq = NEGV;
#pragma unroll
        for (int w0 = 0; w0 < 8; ++w0) {
            s += ps[tid][w0];
            e = fmaxf(e, pe[tid][w0]);
            bq = fmaxf(bq, pb[tid][w0]);
        }
        float lse = __logf(s);
        int gid = blk * 64 + tid;
        if (gid < RTOT) {
            blank_buf[gid] = bq - lse;
            emit_buf[gid]  = e - lse;
        }
    }
}

// ---------------- fused DPs: blocks 0-3 RNNT, 4-7 CTC (64 threads) ---------
__global__ void dp_fused(const float* __restrict__ blank_buf, const float* __restrict__ emit_buf,
                         const float* __restrict__ ctc_logits, const float* __restrict__ ctc_lse,
                         const int* __restrict__ target, const int* __restrict__ frame_len,
                         const int* __restrict__ tgt_len,
                         float* __restrict__ loss_rnnt, float* __restrict__ loss_ctc)
{
    __shared__ float sm[20800];
    const int bid = blockIdx.x;
    const int u = threadIdx.x;   // 64

    if (bid < 4) {
        const int b = bid;
        float (*eb)[52]  = (float(*)[52])sm;            // [200][52]
        float (*bbf)[52] = (float(*)[52])(sm + 10400);  // [200][52]
        for (int idx = u; idx < 200 * 51; idx += 64) {
            int t = idx / 51, uu = idx - t * 51;
            eb[t][uu]  = emit_buf[(b * 200 + t) * 51 + uu];
            bbf[t][uu] = blank_buf[(b * 200 + t) * 51 + uu];
        }
        __syncthreads();
        const int fl = frame_len[b], tl = tgt_len[b];
        const bool act = (u < U1);

        float x = (u < UU) ? eb[0][u] : 0.f;
        float sscan = x;
#pragma unroll
        for (int d = 1; d < 64; d <<= 1) { float o = __shfl_up(sscan, d); if (u >= d) sscan += o; }
        float alpha = sscan - x;
        if (fl - 1 == 0 && u == tl) loss_rnnt[b] = -(alpha + bbf[0][u]);

        for (int t = 1; t < 200; ++t) {
            float blp = act ? bbf[t - 1][u] : NEGV;
            float a = alpha + blp;
            float e = (u < UU) ? eb[t][u] : 0.f;
            float es = e;
#pragma unroll
            for (int d = 1; d < 64; d <<= 1) { float o = __shfl_up(es, d); if (u >= d) es += o; }
            float E = es - e;
            float z = act ? (a - E) : NEGV;
#pragma unroll
            for (int d = 1; d < 64; d <<= 1) { float o = __shfl_up(z, d); if (u >= d) z = lae(z, o); }
            alpha = E + z;
            if (t == fl - 1 && u == tl) loss_rnnt[b] = -(alpha + bbf[t][u]);
        }
    } else {
        const int b = bid - 4;
        float* lpE  = sm;                              // [200] blank lp
        float* lseB = sm + 200;                        // [200]
        float (*lpO)[52] = (float(*)[52])(sm + 400);   // [200][50] raw logits
        for (int idx = u; idx < 200; idx += 64) {
            int bt = b * 200 + idx;
            float ls = ctc_lse[bt];
            lseB[idx] = ls;
            lpE[idx] = ctc_logits[(size_t)bt * VV + (VV - 1)] - ls;
        }
        for (int idx = u; idx < 200 * 50; idx += 64) {
            int t = idx / 50, uu = idx - t * 50;
            int tok = target[b * UU + uu];
            lpO[t][uu] = ctc_logits[(size_t)(b * 200 + t) * VV + tok];
        }
        __syncthreads();
        const int fl = frame_len[b], tl = tgt_len[b];
        bool skip = false;
        if (u >= 1 && u < UU) skip = (target[b * UU + u] != target[b * UU + u - 1]);

        float old_e = (u == 0) ? lpE[0] : NEGV;                   // state 2u
        float old_o = (u == 0) ? (lpO[0][0] - lseB[0]) : NEGV;    // state 2u+1
        if (fl == 1 && u == 0) {
            float a_last = __shfl(old_e, tl);
            float a_prev = __shfl(old_o, tl - 1);
            loss_ctc[b] = -lae(a_last, a_prev);
        }
        for (int t = 1; t < 200; ++t) {
            float prev_o = __shfl_up(old_o, 1);
            if (u == 0) prev_o = NEGV;
            float lp_e = lpE[t];
            float lp_o = (u < UU) ? (lpO[t][u] - lseB[t]) : NEGV;
            float ne = lp_e + lae(old_e, prev_o);
            float no = lp_o + lae3(old_o, old_e, skip ? prev_o : NEGV);
            if (u > 50) ne = NEGV;
            if (u >= 50) no = NEGV;
            old_e = ne; old_o = no;
            if (t == fl - 1) {
                float a_last = __shfl(old_e, tl);
                float a_prev = __shfl(old_o, tl - 1);
                if (u == 0) loss_ctc[b] = -lae(a_last, a_prev);
            }
        }
    }
}

// ---------------- final combine -------------------------------------------
__global__ void combine(const float* __restrict__ lr, const float* __restrict__ lc,
                        float* __restrict__ out)
{
    float r = 0.25f * (lr[0] + lr[1] + lr[2] + lr[3]);
    float c = 0.25f * (lc[0] + lc[1] + lc[2] + lc[3]);
    out[0] = r + 0.3f * c;
}

extern "C" void kernel_launch(void* const* d_in, const int* in_sizes, int n_in,
                              void* d_out, int out_size, void* d_ws, size_t ws_size,
                              hipStream_t stream)
{
    const float* x_enc   = (const float*)d_in[0];
    const float* x_dec   = (const float*)d_in[1];
    const int*   target  = (const int*)d_in[2];
    const int*   frame_l = (const int*)d_in[3];
    const int*   tgt_l   = (const int*)d_in[4];
    const float* W_ctc   = (const float*)d_in[5];
    const float* b_ctc   = (const float*)d_in[6];
    const float* W_enc   = (const float*)d_in[7];
    const float* W_pred  = (const float*)d_in[8];
    const float* b_joint = (const float*)d_in[9];
    const float* W_out   = (const float*)d_in[10];
    const float* b_out   = (const float*)d_in[11];
    float* out = (float*)d_out;

    float* wsf        = (float*)d_ws;
    float* enc_proj   = wsf;                       // 512000
    float* pred_proj  = wsf + 512000;              // 130560
    float* ctc_logits = wsf + 642560;              // 819200
    float* ctc_lse    = wsf + 1461760;             // 832
    float* blank_buf  = wsf + 1462592;             // 40832
    float* emit_buf   = wsf + 1503424;             // 40832
    float* loss_rnnt  = wsf + 1544256;             // 4
    float* loss_ctc   = wsf + 1544260;             // 4 (+pad to 1544272)
    bf16_t* FOut  = (bf16_t*)(wsf + 1544272);      // 655360 bf16
    bf16_t* FEnc  = (bf16_t*)(wsf + 1871952);      // 327680 bf16
    bf16_t* FPred = (bf16_t*)(wsf + 2035792);      // 409600 bf16
    bf16_t* FCtc  = (bf16_t*)(wsf + 2240592);      // 524288 bf16

    pack_all<<<7488, 256, 0, stream>>>(W_out, W_enc, W_pred, W_ctc, FOut, FEnc, FPred, FCtc);
    mfma_gemm3<<<30, 512, 0, stream>>>(x_enc, x_dec, FEnc, FPred, FCtc, b_ctc,
                                       enc_proj, pred_proj, ctc_logits, ctc_lse);
    joint_gemm<<<RPAD / 64, 512, 0, stream>>>(enc_proj, pred_proj, b_joint, FOut, b_out,
                                              target, blank_buf, emit_buf);
    dp_fused<<<8, 64, 0, stream>>>(blank_buf, emit_buf, ctc_logits, ctc_lse,
                                   target, frame_l, tgt_l, loss_rnnt, loss_ctc);
    combine<<<1, 1, 0, stream>>>(loss_rnnt, loss_ctc, out);
}

// Round 3
// 210.356 us; speedup vs baseline: 2.9735x; 1.6534x over previous
//
#include <hip/hip_runtime.h>
#include <hip/hip_bf16.h>

typedef __bf16 bf16_t;
typedef __attribute__((ext_vector_type(4))) __bf16 bf16x4;
typedef __attribute__((ext_vector_type(8))) __bf16 bf16x8;
typedef __attribute__((ext_vector_type(4))) float f32x4;

#define NEGV (-1e30f)

// Problem constants
#define BB 4
#define TT 200
#define UU 50
#define U1 51
#define VV 1024
#define DD 512
#define HH 640
#define RTOT (BB*TT*U1)      // 40800
#define RPAD 40832           // 638*64
#define SS 101

__device__ __forceinline__ float lae(float a, float b) {
    float mx = fmaxf(a, b);
    return mx + __logf(__expf(a - mx) + __expf(b - mx));
}
__device__ __forceinline__ float lae3(float a, float b, float c) {
    float mx = fmaxf(fmaxf(a, b), c);
    return mx + __logf(__expf(a - mx) + __expf(b - mx) + __expf(c - mx));
}
__device__ __forceinline__ float tanh_fast(float x) {
    float ex = __expf(2.f * x);
    return 1.f - 2.f / (ex + 1.f);
}

// ---------------- pack fp32 (K x N) weight into bf16 MFMA B-fragment order.
__device__ __forceinline__ void pack_seg(const float* __restrict__ W, bf16_t* __restrict__ Wf,
                                         int e, int K32, int N)
{
    int j  = e & 7;
    int l  = (e >> 3) & 63;
    int kk = (e >> 9) % K32;
    int nt = e / (K32 * 512);
    int v = nt * 16 + (l & 15);
    int k = kk * 32 + ((l >> 4) << 2) + (j & 3) + ((j >> 2) << 4);
    Wf[e] = (bf16_t)W[(size_t)k * N + v];
}

__global__ void pack_all(const float* __restrict__ Wout, const float* __restrict__ Wenc,
                         const float* __restrict__ Wpred, const float* __restrict__ Wctc,
                         bf16_t* __restrict__ FOut, bf16_t* __restrict__ FEnc,
                         bf16_t* __restrict__ FPred, bf16_t* __restrict__ FCtc)
{
    int e = blockIdx.x * 256 + threadIdx.x;
    if (e < 655360) { pack_seg(Wout, FOut, e, 20, 1024); return; }
    e -= 655360;
    if (e < 327680) { pack_seg(Wenc, FEnc, e, 16, 640); return; }
    e -= 327680;
    if (e < 409600) { pack_seg(Wpred, FPred, e, 20, 640); return; }
    e -= 409600;
    pack_seg(Wctc, FCtc, e, 16, 1024);
}

// ---------------- generic MFMA GEMM: C = A(MxK fp32) @ Wf(packed bf16) -----
template<int K32, int L, bool LSE>
__device__ void gemm_dev(const float* __restrict__ A, int M, int rowbase, int K,
                         const bf16_t* __restrict__ Wf, const float* __restrict__ bias,
                         float* __restrict__ C, float* __restrict__ lse_out, int N,
                         bf16_t* Atile, float (*ps)[8])
{
    const int tid = threadIdx.x;
#pragma unroll 2
    for (int it = 0; it < K32; ++it) {
        int e4 = tid + it * 512;
        int row = e4 / (K32 * 8);
        int c4 = e4 - row * (K32 * 8);
        int c = c4 * 4;
        int arow = rowbase + row; if (arow > M - 1) arow = M - 1;
        const float4 va = *(const float4*)&A[(size_t)arow * K + c];
        int kk = c >> 5, c32 = c & 31, lhi = (c32 >> 2) & 3, b4 = c32 >> 4;
        int j = row >> 4, lrow = row & 15;
        bf16x4 v;
        v[0] = (bf16_t)va.x; v[1] = (bf16_t)va.y; v[2] = (bf16_t)va.z; v[3] = (bf16_t)va.w;
        *(bf16x4*)&Atile[(size_t)(((j * K32 + kk) * 64 + lhi * 16 + lrow) * 8 + b4 * 4)] = v;
    }
    __syncthreads();

    const int l = tid & 63, w = tid >> 6;
    const int lrow = l & 15, lhi = l >> 4;

    f32x4 acc[4][L];
#pragma unroll
    for (int j = 0; j < 4; ++j)
#pragma unroll
        for (int li = 0; li < L; ++li) acc[j][li] = f32x4{0.f, 0.f, 0.f, 0.f};

    for (int kk = 0; kk < K32; ++kk) {
        bf16x8 a[4];
#pragma unroll
        for (int j = 0; j < 4; ++j)
            a[j] = *(const bf16x8*)&Atile[(size_t)(((j * K32 + kk) * 64 + l) * 8)];
#pragma unroll
        for (int li = 0; li < L; ++li) {
            bf16x8 b = *(const bf16x8*)&Wf[(size_t)(((w * L + li) * K32 + kk) * 64 + l) * 8];
#pragma unroll
            for (int j = 0; j < 4; ++j)
                acc[j][li] = __builtin_amdgcn_mfma_f32_16x16x32_bf16(a[j], b, acc[j][li], 0, 0, 0);
        }
    }

    float se[4][4];
    if (LSE) {
#pragma unroll
        for (int j = 0; j < 4; ++j)
#pragma unroll
            for (int i = 0; i < 4; ++i) se[j][i] = 0.f;
    }
#pragma unroll
    for (int j = 0; j < 4; ++j)
#pragma unroll
        for (int li = 0; li < L; ++li) {
            int col = (w * L + li) * 16 + lrow;
            float bv = bias ? bias[col] : 0.f;
#pragma unroll
            for (int i = 0; i < 4; ++i) {
                int grow = rowbase + 16 * j + lhi * 4 + i;
                float x = acc[j][li][i] + bv;
                if (grow < M) C[(size_t)grow * N + col] = x;
                if (LSE) se[j][i] += __expf(x);
            }
        }
    if (LSE) {
#pragma unroll
        for (int d = 1; d < 16; d <<= 1)
#pragma unroll
            for (int j = 0; j < 4; ++j)
#pragma unroll
                for (int i = 0; i < 4; ++i) se[j][i] += __shfl_xor(se[j][i], d);
        if (lrow == 0) {
#pragma unroll
            for (int j = 0; j < 4; ++j)
#pragma unroll
                for (int i = 0; i < 4; ++i) ps[16 * j + lhi * 4 + i][w] = se[j][i];
        }
        __syncthreads();
        if (tid < 64) {
            float s = 0.f;
#pragma unroll
            for (int w0 = 0; w0 < 8; ++w0) s += ps[tid][w0];
            int grow = rowbase + tid;
            if (grow < M) lse_out[grow] = __logf(s);
        }
    }
}

__global__ __launch_bounds__(512)
void mfma_gemm3(const float* __restrict__ x_enc, const float* __restrict__ x_dec,
                const bf16_t* __restrict__ FEnc, const bf16_t* __restrict__ FPred,
                const bf16_t* __restrict__ FCtc, const float* __restrict__ b_ctc,
                float* __restrict__ enc_proj, float* __restrict__ pred_proj,
                float* __restrict__ ctc_logits, float* __restrict__ ctc_lse)
{
    __shared__ bf16_t Atile[40960];
    __shared__ float ps[64][8];
    int blk = blockIdx.x;
    if (blk < 13)
        gemm_dev<16, 5, false>(x_enc, 800, blk * 64, 512, FEnc, nullptr, enc_proj, nullptr, 640, Atile, ps);
    else if (blk < 17)
        gemm_dev<20, 5, false>(x_dec, 204, (blk - 13) * 64, 640, FPred, nullptr, pred_proj, nullptr, 640, Atile, ps);
    else
        gemm_dev<16, 8, true>(x_enc, 800, (blk - 17) * 64, 512, FCtc, b_ctc, ctc_logits, ctc_lse, 1024, Atile, ps);
}

// ---------------- fused joint build + MFMA GEMM + row-LSE + gather ---------
__global__ __launch_bounds__(512)
void joint_gemm(const float* __restrict__ enc,   // (800,640)
                const float* __restrict__ pred,  // (204,640)
                const float* __restrict__ bj,    // (640)
                const bf16_t* __restrict__ Wf,   // packed (K32=20, NT=64)
                const float* __restrict__ bo,    // (1024)
                const int* __restrict__ target,  // (4,50)
                float* __restrict__ blank_buf, float* __restrict__ emit_buf)
{
    __shared__ bf16_t Afrag[40960];              // 64 rows x 640 K, frag order
    __shared__ int rowBT[64], rowBU[64], rowTG[64];
    __shared__ float ps[64][8], pe[64][8], pb[64][8];
    const int tid = threadIdx.x;
    const int blk = blockIdx.x;

    if (tid < 64) {
        int r = blk * 64 + tid; if (r > RTOT - 1) r = RTOT - 1;
        int b = r / (TT * U1); int rem = r - b * (TT * U1);
        int t = rem / U1;      int u = rem - t * U1;
        rowBT[tid] = b * TT + t;
        rowBU[tid] = b * U1 + u;
        rowTG[tid] = (u < UU) ? target[b * UU + u] : -1;
    }
    __syncthreads();

#pragma unroll 2
    for (int it = 0; it < 20; ++it) {
        int e4 = tid + it * 512;
        int row = e4 / 160, c4 = e4 - row * 160;
        int c = c4 * 4;
        const float4 ve = *(const float4*)&enc[(size_t)rowBT[row] * HH + c];
        const float4 vp = *(const float4*)&pred[(size_t)rowBU[row] * HH + c];
        const float4 vb = *(const float4*)&bj[c];
        int kk = c >> 5, c32 = c & 31, lhi = (c32 >> 2) & 3, b4 = c32 >> 4;
        int j = row >> 4, lrow = row & 15;
        bf16x4 v;
        v[0] = (bf16_t)tanh_fast(ve.x + vp.x + vb.x);
        v[1] = (bf16_t)tanh_fast(ve.y + vp.y + vb.y);
        v[2] = (bf16_t)tanh_fast(ve.z + vp.z + vb.z);
        v[3] = (bf16_t)tanh_fast(ve.w + vp.w + vb.w);
        *(bf16x4*)&Afrag[(size_t)(((j * 20 + kk) * 64 + lhi * 16 + lrow) * 8 + b4 * 4)] = v;
    }
    __syncthreads();

    const int l = tid & 63, w = tid >> 6;
    const int lrow = l & 15, lhi = l >> 4;

    f32x4 acc[4][8];
#pragma unroll
    for (int j = 0; j < 4; ++j)
#pragma unroll
        for (int li = 0; li < 8; ++li) acc[j][li] = f32x4{0.f, 0.f, 0.f, 0.f};

    for (int kk = 0; kk < 20; ++kk) {
        bf16x8 a[4];
#pragma unroll
        for (int j = 0; j < 4; ++j)
            a[j] = *(const bf16x8*)&Afrag[(size_t)(((j * 20 + kk) * 64 + l) * 8)];
#pragma unroll
        for (int li = 0; li < 8; ++li) {
            bf16x8 b = *(const bf16x8*)&Wf[(size_t)(((w * 8 + li) * 20 + kk) * 64 + l) * 8];
#pragma unroll
            for (int j = 0; j < 4; ++j)
                acc[j][li] = __builtin_amdgcn_mfma_f32_16x16x32_bf16(a[j], b, acc[j][li], 0, 0, 0);
        }
    }

    int tg[4][4];
#pragma unroll
    for (int j = 0; j < 4; ++j)
#pragma unroll
        for (int i = 0; i < 4; ++i) tg[j][i] = rowTG[16 * j + lhi * 4 + i];

    float se[4][4], ee[4][4], bbv[4][4];
#pragma unroll
    for (int j = 0; j < 4; ++j)
#pragma unroll
        for (int i = 0; i < 4; ++i) { se[j][i] = 0.f; ee[j][i] = NEGV; bbv[j][i] = NEGV; }

#pragma unroll
    for (int li = 0; li < 8; ++li) {
        int col = (w * 8 + li) * 16 + lrow;
        float bv = bo[col];
#pragma unroll
        for (int j = 0; j < 4; ++j)
#pragma unroll
            for (int i = 0; i < 4; ++i) {
                float x = acc[j][li][i] + bv;
                se[j][i] += __expf(x);
                if (col == tg[j][i]) ee[j][i] = x;
                if (col == VV - 1) bbv[j][i] = x;
            }
    }
#pragma unroll
    for (int d = 1; d < 16; d <<= 1)
#pragma unroll
        for (int j = 0; j < 4; ++j)
#pragma unroll
            for (int i = 0; i < 4; ++i) {
                se[j][i] += __shfl_xor(se[j][i], d);
                ee[j][i] = fmaxf(ee[j][i], __shfl_xor(ee[j][i], d));
                bbv[j][i] = fmaxf(bbv[j][i], __shfl_xor(bbv[j][i], d));
            }
    if (lrow == 0) {
#pragma unroll
        for (int j = 0; j < 4; ++j)
#pragma unroll
            for (int i = 0; i < 4; ++i) {
                int r = 16 * j + lhi * 4 + i;
                ps[r][w] = se[j][i]; pe[r][w] = ee[j][i]; pb[r][w] = bbv[j][i];
            }
    }
    __syncthreads();
    if (tid < 64) {
        float s = 0.f, e = NEGV, bq = NEGV;
#pragma unroll
        for (int w0 = 0; w0 < 8; ++w0) {
            s += ps[tid][w0];
            e = fmaxf(e, pe[tid][w0]);
            bq = fmaxf(bq, pb[tid][w0]);
        }
        float lse = __logf(s);
        int gid = blk * 64 + tid;
        if (gid < RTOT) {
            blank_buf[gid] = bq - lse;
            emit_buf[gid]  = e - lse;
        }
    }
}

// ---------------- fused DPs: blocks 0-3 RNNT (wavefront), 4-7 CTC ----------
__global__ void dp_fused(const float* __restrict__ blank_buf, const float* __restrict__ emit_buf,
                         const float* __restrict__ ctc_logits, const float* __restrict__ ctc_lse,
                         const int* __restrict__ target, const int* __restrict__ frame_len,
                         const int* __restrict__ tgt_len,
                         float* __restrict__ loss_rnnt, float* __restrict__ loss_ctc)
{
    __shared__ float sm[20800];
    const int bid = blockIdx.x;
    const int u = threadIdx.x;   // 64

    if (bid < 4) {
        // ---- RNNT anti-diagonal wavefront: lane u owns column u ----
        const int b = bid;
        float2* pk = (float2*)sm;    // [52][200]: (blank[t][u], emit[t][u]) at pk[u*200+t]
        for (int i = u; i < U1 * TT; i += 64) {
            int uu = i / TT, t = i - uu * TT;
            float bl = blank_buf[(b * TT + t) * U1 + uu];
            float em = emit_buf[(b * TT + t) * U1 + uu];
            pk[uu * TT + t] = make_float2(bl, em);
        }
        __syncthreads();
        const int fl = frame_len[b], tl = tgt_len[b];
        float A = (u == 0) ? 0.f : NEGV;     // alpha[0][0]=0
        if (fl == 1 && tl == 0 && u == 0) loss_rnnt[b] = -(A + pk[0].x);
        // diagonals d = t+u, d = 1..249; 1 shfl + 1 lae per step
        for (int d = 1; d <= TT + U1 - 2; ++d) {
            int x = d - 1 - u;                       // = current t of this lane
            int xc = min(max(x, 0), TT - 1);
            int uc = min(u, U1);                     // row 51 exists as scratch
            float2 be = pk[uc * TT + xc];            // (blank[x][u], emit[x][u])
            float vshare = A + be.y;                 // alpha[x][u] + emit[x][u]
            float left = __shfl_up(vshare, 1);
            if (u == 0) left = NEGV;
            int t_new = d - u;
            if (u < U1 && t_new >= 0 && t_new < TT) {
                float up = (t_new >= 1) ? (A + be.x) : NEGV;  // be.x = blank[t_new-1][u]
                A = lae(up, left);
                if (t_new == fl - 1 && u == tl)
                    loss_rnnt[b] = -(A + pk[u * TT + t_new].x);
            }
        }
    } else {
        // ---- CTC: 2 states per lane, 200 serial t-steps ----
        const int b = bid - 4;
        float* lpE  = sm;                              // [200] blank lp
        float* lseB = sm + 200;                        // [200]
        float (*lpO)[52] = (float(*)[52])(sm + 400);   // [200][50] raw logits
        for (int idx = u; idx < 200; idx += 64) {
            int bt = b * 200 + idx;
            float ls = ctc_lse[bt];
            lseB[idx] = ls;
            lpE[idx] = ctc_logits[(size_t)bt * VV + (VV - 1)] - ls;
        }
        for (int idx = u; idx < 200 * 50; idx += 64) {
            int t = idx / 50, uu = idx - t * 50;
            int tok = target[b * UU + uu];
            lpO[t][uu] = ctc_logits[(size_t)(b * 200 + t) * VV + tok];
        }
        __syncthreads();
        const int fl = frame_len[b], tl = tgt_len[b];
        bool skip = false;
        if (u >= 1 && u < UU) skip = (target[b * UU + u] != target[b * UU + u - 1]);

        float old_e = (u == 0) ? lpE[0] : NEGV;                   // state 2u
        float old_o = (u == 0) ? (lpO[0][0] - lseB[0]) : NEGV;    // state 2u+1
        if (fl == 1 && u == 0) {
            float a_last = __shfl(old_e, tl);
            float a_prev = __shfl(old_o, tl - 1);
            loss_ctc[b] = -lae(a_last, a_prev);
        }
        for (int t = 1; t < 200; ++t) {
            float prev_o = __shfl_up(old_o, 1);
            if (u == 0) prev_o = NEGV;
            float lp_e = lpE[t];
            float lp_o = (u < UU) ? (lpO[t][u] - lseB[t]) : NEGV;
            float ne = lp_e + lae(old_e, prev_o);
            float no = lp_o + lae3(old_o, old_e, skip ? prev_o : NEGV);
            if (u > 50) ne = NEGV;
            if (u >= 50) no = NEGV;
            old_e = ne; old_o = no;
            if (t == fl - 1) {
                float a_last = __shfl(old_e, tl);
                float a_prev = __shfl(old_o, tl - 1);
                if (u == 0) loss_ctc[b] = -lae(a_last, a_prev);
            }
        }
    }
}

// ---------------- final combine -------------------------------------------
__global__ void combine(const float* __restrict__ lr, const float* __restrict__ lc,
                        float* __restrict__ out)
{
    float r = 0.25f * (lr[0] + lr[1] + lr[2] + lr[3]);
    float c = 0.25f * (lc[0] + lc[1] + lc[2] + lc[3]);
    out[0] = r + 0.3f * c;
}

extern "C" void kernel_launch(void* const* d_in, const int* in_sizes, int n_in,
                              void* d_out, int out_size, void* d_ws, size_t ws_size,
                              hipStream_t stream)
{
    const float* x_enc   = (const float*)d_in[0];
    const float* x_dec   = (const float*)d_in[1];
    const int*   target  = (const int*)d_in[2];
    const int*   frame_l = (const int*)d_in[3];
    const int*   tgt_l   = (const int*)d_in[4];
    const float* W_ctc   = (const float*)d_in[5];
    const float* b_ctc   = (const float*)d_in[6];
    const float* W_enc   = (const float*)d_in[7];
    const float* W_pred  = (const float*)d_in[8];
    const float* b_joint = (const float*)d_in[9];
    const float* W_out   = (const float*)d_in[10];
    const float* b_out   = (const float*)d_in[11];
    float* out = (float*)d_out;

    float* wsf        = (float*)d_ws;
    float* enc_proj   = wsf;                       // 512000
    float* pred_proj  = wsf + 512000;              // 130560
    float* ctc_logits = wsf + 642560;              // 819200
    float* ctc_lse    = wsf + 1461760;             // 832
    float* blank_buf  = wsf + 1462592;             // 40832
    float* emit_buf   = wsf + 1503424;             // 40832
    float* loss_rnnt  = wsf + 1544256;             // 4
    float* loss_ctc   = wsf + 1544260;             // 4 (+pad to 1544272)
    bf16_t* FOut  = (bf16_t*)(wsf + 1544272);      // 655360 bf16
    bf16_t* FEnc  = (bf16_t*)(wsf + 1871952);      // 327680 bf16
    bf16_t* FPred = (bf16_t*)(wsf + 2035792);      // 409600 bf16
    bf16_t* FCtc  = (bf16_t*)(wsf + 2240592);      // 524288 bf16

    pack_all<<<7488, 256, 0, stream>>>(W_out, W_enc, W_pred, W_ctc, FOut, FEnc, FPred, FCtc);
    mfma_gemm3<<<30, 512, 0, stream>>>(x_enc, x_dec, FEnc, FPred, FCtc, b_ctc,
                                       enc_proj, pred_proj, ctc_logits, ctc_lse);
    joint_gemm<<<RPAD / 64, 512, 0, stream>>>(enc_proj, pred_proj, b_joint, FOut, b_out,
                                              target, blank_buf, emit_buf);
    dp_fused<<<8, 64, 0, stream>>>(blank_buf, emit_buf, ctc_logits, ctc_lse,
                                   target, frame_l, tgt_l, loss_rnnt, loss_ctc);
    combine<<<1, 1, 0, stream>>>(loss_rnnt, loss_ctc, out);
}